// Round 5
// baseline (110.487 us; speedup 1.0000x reference)
//
#include <hip/hip_runtime.h>
#include <math.h>

#define B_      16
#define C_IN_   128
#define C_OUT_  3
#define W_DIM_  512
#define HW_     65536          // 256*256
#define CONV_CLAMP_ 256.0f

typedef float f32x4 __attribute__((ext_vector_type(4)));

// ---------------------------------------------------------------------------
// k_prep: fused styles + eff. One block per batch b (16 blocks).
//   s[j]      = dot(w[b], affine_w[j]) / sqrt(512) + affine_b[j]   (j=0..383)
//   style[i]  = (s[i]*s[i+128] + s[i+256]) / sqrt(128)
//   eff[b][i] = f32x4(style*weight[0][i], style*weight[1][i],
//                     style*weight[2][i], 0)
// ---------------------------------------------------------------------------
__global__ __launch_bounds__(256) void k_prep(
        const float* __restrict__ w,
        const float* __restrict__ affine_w,
        const float* __restrict__ affine_b,
        const float* __restrict__ weight,
        float* __restrict__ eff) {
    __shared__ f32x4 w_sh[W_DIM_ / 4];      // 128 f32x4 = w row (2 KB)
    __shared__ float s_sh[3 * C_IN_];       // 384 styles
    int b = blockIdx.x;

    if (threadIdx.x < W_DIM_ / 4)
        w_sh[threadIdx.x] =
            reinterpret_cast<const f32x4*>(w + (size_t)b * W_DIM_)[threadIdx.x];
    __syncthreads();

    int group = threadIdx.x >> 4;           // 16 groups of 16 lanes
    int lane  = threadIdx.x & 15;
    #pragma unroll
    for (int j0 = 0; j0 < 24; ++j0) {
        int j = group + j0 * 16;            // 16 groups * 24 iters = 384 rows
        const f32x4* arow =
            reinterpret_cast<const f32x4*>(affine_w + (size_t)j * W_DIM_);
        float p = 0.f;
        #pragma unroll
        for (int t = 0; t < 8; ++t) {
            f32x4 av = arow[lane + t * 16];
            f32x4 wv = w_sh[lane + t * 16];
            p = fmaf(av.x, wv.x, p);
            p = fmaf(av.y, wv.y, p);
            p = fmaf(av.z, wv.z, p);
            p = fmaf(av.w, wv.w, p);
        }
        #pragma unroll
        for (int off = 8; off; off >>= 1)
            p += __shfl_xor(p, off, 16);
        if (lane == 0)
            s_sh[j] = fmaf(p, 0.04419417382415922f /*1/sqrt(512)*/, affine_b[j]);
    }
    __syncthreads();

    if (threadIdx.x < C_IN_) {
        int i = threadIdx.x;
        float style = fmaf(s_sh[i], s_sh[i + C_IN_], s_sh[i + 2 * C_IN_])
                      * 0.08838834764831845f;   // 1/sqrt(128)
        f32x4 e;
        e.x = style * weight[0 * C_IN_ + i];
        e.y = style * weight[1 * C_IN_ + i];
        e.z = style * weight[2 * C_IN_ + i];
        e.w = 0.f;
        reinterpret_cast<f32x4*>(eff)[b * C_IN_ + i] = e;
    }
}

// ---------------------------------------------------------------------------
// k_main — byte-identical to the R4 winner (102.5 us control).
// 1024 blocks (64/batch), 256 thr, 4 px/thread, NT loads/stores.
// ---------------------------------------------------------------------------
__global__ __launch_bounds__(256) void k_main(
        const float* __restrict__ x,
        const float* __restrict__ eff,
        const float* __restrict__ bias,
        float* __restrict__ out) {
    __shared__ f32x4 eff_lds[C_IN_];
    int b   = blockIdx.x >> 6;       // 64 blocks per batch
    int blk = blockIdx.x & 63;

    if (threadIdx.x < C_IN_)
        eff_lds[threadIdx.x] =
            reinterpret_cast<const f32x4*>(eff)[b * C_IN_ + threadIdx.x];
    __syncthreads();

    int pix = blk * 1024 + threadIdx.x * 4;     // 256 thr * 4 px = 1024 px
    const float* xb = x + (size_t)b * C_IN_ * HW_ + pix;

    f32x4 a0 = {0.f,0.f,0.f,0.f};
    f32x4 a1 = {0.f,0.f,0.f,0.f};
    f32x4 a2 = {0.f,0.f,0.f,0.f};

    #pragma unroll 8
    for (int i = 0; i < C_IN_; ++i) {
        f32x4 xv = __builtin_nontemporal_load(
            reinterpret_cast<const f32x4*>(xb + ((size_t)i << 16)));
        f32x4 e  = eff_lds[i];
        a0.x = fmaf(xv.x, e.x, a0.x);
        a0.y = fmaf(xv.y, e.x, a0.y);
        a0.z = fmaf(xv.z, e.x, a0.z);
        a0.w = fmaf(xv.w, e.x, a0.w);
        a1.x = fmaf(xv.x, e.y, a1.x);
        a1.y = fmaf(xv.y, e.y, a1.y);
        a1.z = fmaf(xv.z, e.y, a1.z);
        a1.w = fmaf(xv.w, e.y, a1.w);
        a2.x = fmaf(xv.x, e.z, a2.x);
        a2.y = fmaf(xv.y, e.z, a2.y);
        a2.z = fmaf(xv.z, e.z, a2.z);
        a2.w = fmaf(xv.w, e.z, a2.w);
    }

    float b0 = bias[0], b1 = bias[1], b2 = bias[2];
    auto clip4 = [](f32x4 v, float bb) {
        f32x4 r;
        r.x = fminf(fmaxf(v.x + bb, -CONV_CLAMP_), CONV_CLAMP_);
        r.y = fminf(fmaxf(v.y + bb, -CONV_CLAMP_), CONV_CLAMP_);
        r.z = fminf(fmaxf(v.z + bb, -CONV_CLAMP_), CONV_CLAMP_);
        r.w = fminf(fmaxf(v.w + bb, -CONV_CLAMP_), CONV_CLAMP_);
        return r;
    };

    float* ob = out + (size_t)b * C_OUT_ * HW_ + pix;
    __builtin_nontemporal_store(clip4(a0, b0), reinterpret_cast<f32x4*>(ob));
    __builtin_nontemporal_store(clip4(a1, b1), reinterpret_cast<f32x4*>(ob + HW_));
    __builtin_nontemporal_store(clip4(a2, b2), reinterpret_cast<f32x4*>(ob + 2 * HW_));
}

// ---------------------------------------------------------------------------
extern "C" void kernel_launch(void* const* d_in, const int* in_sizes, int n_in,
                              void* d_out, int out_size, void* d_ws, size_t ws_size,
                              hipStream_t stream) {
    const float* x        = (const float*)d_in[0];
    const float* w        = (const float*)d_in[1];
    const float* weight   = (const float*)d_in[2];
    const float* bias     = (const float*)d_in[3];
    const float* affine_w = (const float*)d_in[4];
    const float* affine_b = (const float*)d_in[5];
    float* out = (float*)d_out;

    float* eff = (float*)d_ws;                      // 16*128 f32x4

    k_prep<<<B_,   256, 0, stream>>>(w, affine_w, affine_b, weight, eff);
    k_main<<<1024, 256, 0, stream>>>(x, eff, bias, out);
}

// Round 6
// 100.254 us; speedup vs baseline: 1.1021x; 1.1021x over previous
//
#include <hip/hip_runtime.h>
#include <math.h>

#define B_      16
#define C_IN_   128
#define C_OUT_  3
#define W_DIM_  512
#define HW_     65536          // 256*256
#define CONV_CLAMP_ 256.0f

typedef float f32x4 __attribute__((ext_vector_type(4)));

// ---------------------------------------------------------------------------
// k_prep1: single-launch prologue, fully parallel.
// One 16-lane group per (b,i): computes the three dots
//   m_k = dot(w[b], affine_w[k*128+i]) / sqrt(512) + affine_b[k*128+i]
// then style = (m1*m2+m3)/sqrt(128) and eff[b][i] directly.
// 2048 groups -> 128 blocks * 256 threads. affine_w read exactly once,
// coalesced (16 lanes * 16 B = 256 B per instr), spread over 128 blocks.
// ---------------------------------------------------------------------------
__global__ __launch_bounds__(256) void k_prep1(
        const float* __restrict__ w,
        const float* __restrict__ affine_w,
        const float* __restrict__ affine_b,
        const float* __restrict__ weight,
        float* __restrict__ eff) {
    int gid   = blockIdx.x * blockDim.x + threadIdx.x;
    int group = gid >> 4;            // (b,i) pair, 0..2047
    int lane  = gid & 15;
    int b = group >> 7;              // group / 128
    int i = group & 127;

    const f32x4* wr4 = reinterpret_cast<const f32x4*>(w + (size_t)b * W_DIM_);

    float p0 = 0.f, p1 = 0.f, p2 = 0.f;
    const f32x4* a0r = reinterpret_cast<const f32x4*>(affine_w + (size_t)(i)          * W_DIM_);
    const f32x4* a1r = reinterpret_cast<const f32x4*>(affine_w + (size_t)(i + 128)    * W_DIM_);
    const f32x4* a2r = reinterpret_cast<const f32x4*>(affine_w + (size_t)(i + 256)    * W_DIM_);
    #pragma unroll
    for (int t = 0; t < 8; ++t) {
        f32x4 wv = wr4[lane + t * 16];
        f32x4 av0 = a0r[lane + t * 16];
        f32x4 av1 = a1r[lane + t * 16];
        f32x4 av2 = a2r[lane + t * 16];
        p0 = fmaf(av0.x, wv.x, p0); p0 = fmaf(av0.y, wv.y, p0);
        p0 = fmaf(av0.z, wv.z, p0); p0 = fmaf(av0.w, wv.w, p0);
        p1 = fmaf(av1.x, wv.x, p1); p1 = fmaf(av1.y, wv.y, p1);
        p1 = fmaf(av1.z, wv.z, p1); p1 = fmaf(av1.w, wv.w, p1);
        p2 = fmaf(av2.x, wv.x, p2); p2 = fmaf(av2.y, wv.y, p2);
        p2 = fmaf(av2.z, wv.z, p2); p2 = fmaf(av2.w, wv.w, p2);
    }
    #pragma unroll
    for (int off = 8; off; off >>= 1) {
        p0 += __shfl_xor(p0, off, 16);
        p1 += __shfl_xor(p1, off, 16);
        p2 += __shfl_xor(p2, off, 16);
    }
    if (lane == 0) {
        const float g = 0.04419417382415922f;     // 1/sqrt(512)
        float m1 = fmaf(p0, g, affine_b[i]);
        float m2 = fmaf(p1, g, affine_b[i + 128]);
        float m3 = fmaf(p2, g, affine_b[i + 256]);
        float style = fmaf(m1, m2, m3) * 0.08838834764831845f;  // 1/sqrt(128)
        f32x4 e;
        e.x = style * weight[0 * C_IN_ + i];
        e.y = style * weight[1 * C_IN_ + i];
        e.z = style * weight[2 * C_IN_ + i];
        e.w = 0.f;
        reinterpret_cast<f32x4*>(eff)[group] = e;
    }
}

// ---------------------------------------------------------------------------
// k_main — byte-identical to the R4 winner (102.5 us control).
// 1024 blocks (64/batch), 256 thr, 4 px/thread, NT loads/stores.
// ---------------------------------------------------------------------------
__global__ __launch_bounds__(256) void k_main(
        const float* __restrict__ x,
        const float* __restrict__ eff,
        const float* __restrict__ bias,
        float* __restrict__ out) {
    __shared__ f32x4 eff_lds[C_IN_];
    int b   = blockIdx.x >> 6;       // 64 blocks per batch
    int blk = blockIdx.x & 63;

    if (threadIdx.x < C_IN_)
        eff_lds[threadIdx.x] =
            reinterpret_cast<const f32x4*>(eff)[b * C_IN_ + threadIdx.x];
    __syncthreads();

    int pix = blk * 1024 + threadIdx.x * 4;     // 256 thr * 4 px = 1024 px
    const float* xb = x + (size_t)b * C_IN_ * HW_ + pix;

    f32x4 a0 = {0.f,0.f,0.f,0.f};
    f32x4 a1 = {0.f,0.f,0.f,0.f};
    f32x4 a2 = {0.f,0.f,0.f,0.f};

    #pragma unroll 8
    for (int i = 0; i < C_IN_; ++i) {
        f32x4 xv = __builtin_nontemporal_load(
            reinterpret_cast<const f32x4*>(xb + ((size_t)i << 16)));
        f32x4 e  = eff_lds[i];
        a0.x = fmaf(xv.x, e.x, a0.x);
        a0.y = fmaf(xv.y, e.x, a0.y);
        a0.z = fmaf(xv.z, e.x, a0.z);
        a0.w = fmaf(xv.w, e.x, a0.w);
        a1.x = fmaf(xv.x, e.y, a1.x);
        a1.y = fmaf(xv.y, e.y, a1.y);
        a1.z = fmaf(xv.z, e.y, a1.z);
        a1.w = fmaf(xv.w, e.y, a1.w);
        a2.x = fmaf(xv.x, e.z, a2.x);
        a2.y = fmaf(xv.y, e.z, a2.y);
        a2.z = fmaf(xv.z, e.z, a2.z);
        a2.w = fmaf(xv.w, e.z, a2.w);
    }

    float b0 = bias[0], b1 = bias[1], b2 = bias[2];
    auto clip4 = [](f32x4 v, float bb) {
        f32x4 r;
        r.x = fminf(fmaxf(v.x + bb, -CONV_CLAMP_), CONV_CLAMP_);
        r.y = fminf(fmaxf(v.y + bb, -CONV_CLAMP_), CONV_CLAMP_);
        r.z = fminf(fmaxf(v.z + bb, -CONV_CLAMP_), CONV_CLAMP_);
        r.w = fminf(fmaxf(v.w + bb, -CONV_CLAMP_), CONV_CLAMP_);
        return r;
    };

    float* ob = out + (size_t)b * C_OUT_ * HW_ + pix;
    __builtin_nontemporal_store(clip4(a0, b0), reinterpret_cast<f32x4*>(ob));
    __builtin_nontemporal_store(clip4(a1, b1), reinterpret_cast<f32x4*>(ob + HW_));
    __builtin_nontemporal_store(clip4(a2, b2), reinterpret_cast<f32x4*>(ob + 2 * HW_));
}

// ---------------------------------------------------------------------------
extern "C" void kernel_launch(void* const* d_in, const int* in_sizes, int n_in,
                              void* d_out, int out_size, void* d_ws, size_t ws_size,
                              hipStream_t stream) {
    const float* x        = (const float*)d_in[0];
    const float* w        = (const float*)d_in[1];
    const float* weight   = (const float*)d_in[2];
    const float* bias     = (const float*)d_in[3];
    const float* affine_w = (const float*)d_in[4];
    const float* affine_b = (const float*)d_in[5];
    float* out = (float*)d_out;

    float* eff = (float*)d_ws;                      // 16*128 f32x4

    k_prep1<<<128,  256, 0, stream>>>(w, affine_w, affine_b, weight, eff);
    k_main <<<1024, 256, 0, stream>>>(x, eff, bias, out);
}